// Round 1
// baseline (229.985 us; speedup 1.0000x reference)
//
#include <hip/hip_runtime.h>
#include <hip/hip_bf16.h>

#define B_ 2
#define S_ 2048
#define D_ 1024
#define H_ 16
#define KVH_ 4
#define HD_ 64

typedef __attribute__((ext_vector_type(4))) float f32x4;
typedef __attribute__((ext_vector_type(8))) short short8;

#define DEV static __device__ __forceinline__

DEV unsigned short f2bf(float f) {
  union { float f; unsigned int u; } v; v.f = f;
  unsigned int r = v.u + 0x7FFFu + ((v.u >> 16) & 1u);
  return (unsigned short)(r >> 16);
}

DEV void gload_lds16(const void* g, void* l) {
  __builtin_amdgcn_global_load_lds(
      (const __attribute__((address_space(1))) unsigned int*)g,
      (__attribute__((address_space(3))) unsigned int*)l, 16, 0, 0);
}

__global__ __launch_bounds__(256) void cast_kernel(const float* __restrict__ src,
                                                   unsigned short* __restrict__ dst, int n4) {
  int i = blockIdx.x * 256 + threadIdx.x;
  if (i >= n4) return;
  float4 v = ((const float4*)src)[i];
  ushort4 o;
  o.x = f2bf(v.x); o.y = f2bf(v.y); o.z = f2bf(v.z); o.w = f2bf(v.w);
  ((ushort4*)dst)[i] = o;
}

// C = A (M x K, bf16 row-major) @ Bw^T (Bw is N x K bf16 row-major)
// MODE 0: plain fp32 C. MODE 1: qkv scatter (bf16): cols 0-1023 -> q[b][h][s][d],
// 1024-1279 -> k[b][kvh][s][d], 1280-1535 -> v[b][kvh][d][s] (transposed).
template <int MODE>
__global__ __launch_bounds__(256) void gemm_bt(
    const unsigned short* __restrict__ A, const unsigned short* __restrict__ Bw,
    float* __restrict__ C, unsigned short* __restrict__ qb,
    unsigned short* __restrict__ kb, unsigned short* __restrict__ vb,
    int M, int N, int K, int ntn) {
  __shared__ __align__(16) unsigned short As[128 * 64];
  __shared__ __align__(16) unsigned short Bs[128 * 64];
  const int tid = threadIdx.x;
  const int lane = tid & 63, wid = tid >> 6;
  const int wr = wid >> 1, wc = wid & 1;
  const int tm = blockIdx.x / ntn, tn = blockIdx.x % ntn;
  const int row0 = tm * 128, col0 = tn * 128;
  f32x4 acc[4][4] = {};
  const int sr = tid >> 3, sc = (tid & 7) * 8;
  for (int kt = 0; kt < K; kt += 64) {
    __syncthreads();
#pragma unroll
    for (int i = 0; i < 4; ++i) {
      gload_lds16(A + (size_t)(row0 + i * 32 + sr) * K + kt + sc,
                  (void*)(As + i * 2048 + tid * 8));
      gload_lds16(Bw + (size_t)(col0 + i * 32 + sr) * K + kt + sc,
                  (void*)(Bs + i * 2048 + tid * 8));
    }
    __syncthreads();
#pragma unroll
    for (int ks = 0; ks < 64; ks += 32) {
      const int fc = ks + (lane >> 4) * 8;
      short8 af[4], bf[4];
#pragma unroll
      for (int m = 0; m < 4; ++m)
        af[m] = *(const short8*)&As[(wr * 64 + m * 16 + (lane & 15)) * 64 + fc];
#pragma unroll
      for (int n = 0; n < 4; ++n)
        bf[n] = *(const short8*)&Bs[(wc * 64 + n * 16 + (lane & 15)) * 64 + fc];
#pragma unroll
      for (int m = 0; m < 4; ++m)
#pragma unroll
        for (int n = 0; n < 4; ++n)
          acc[m][n] = __builtin_amdgcn_mfma_f32_16x16x32_bf16(af[m], bf[n], acc[m][n], 0, 0, 0);
    }
  }
#pragma unroll
  for (int m = 0; m < 4; ++m)
#pragma unroll
    for (int n = 0; n < 4; ++n)
#pragma unroll
      for (int j = 0; j < 4; ++j) {
        const int grow = row0 + wr * 64 + m * 16 + (lane >> 4) * 4 + j;
        const int gcol = col0 + wc * 64 + n * 16 + (lane & 15);
        const float v = acc[m][n][j];
        if (MODE == 0) {
          C[(size_t)grow * N + gcol] = v;
        } else {
          const int b = grow >> 11, s = grow & 2047;
          const unsigned short hv = f2bf(v);
          if (gcol < 1024) {
            const int hh = gcol >> 6, d = gcol & 63;
            qb[(((size_t)b * H_ + hh) * S_ + s) * HD_ + d] = hv;
          } else if (gcol < 1280) {
            const int kk = (gcol - 1024) >> 6, d = gcol & 63;
            kb[(((size_t)b * KVH_ + kk) * S_ + s) * HD_ + d] = hv;
          } else {
            const int kk = (gcol - 1280) >> 6, d = gcol & 63;
            vb[(((size_t)b * KVH_ + kk) * HD_ + d) * S_ + s] = hv;
          }
        }
      }
}

// One block = (b, mask-group g, 32-row q tile). 8 waves = 8 q-heads of the group.
// Shares one mask tile + 2 kv-heads' K/V tiles in LDS across all 8 heads.
__global__ __launch_bounds__(512) void attn_kernel(
    const unsigned short* __restrict__ qb, const unsigned short* __restrict__ kb,
    const unsigned short* __restrict__ vb, const float* __restrict__ fmask,
    const float* __restrict__ tmask, unsigned short* __restrict__ attnb) {
  __shared__ __align__(16) unsigned short Ks[2 * 64 * 64];
  __shared__ __align__(16) unsigned short Vs[2 * 64 * 64];  // [d][s_local]
  __shared__ __align__(16) float Ms[32 * 64];
  __shared__ __align__(16) unsigned short Ps[8 * 32 * 64];
  const int bid = blockIdx.x;
  const int qt = bid & 63, g = (bid >> 6) & 1, b = bid >> 7;
  const int tid = threadIdx.x, lane = tid & 63, w = tid >> 6;
  const int hq = g * 8 + w;
  const int kvl = w >> 2;
  const float* mask = (g ? tmask : fmask) + ((size_t)b * S_ + qt * 32) * S_;
  short8 aq[2][2];
  {
    const unsigned short* qbase = qb + (((size_t)b * H_ + hq) * S_ + qt * 32) * HD_;
#pragma unroll
    for (int m = 0; m < 2; ++m)
#pragma unroll
      for (int ks = 0; ks < 2; ++ks)
        aq[m][ks] = *(const short8*)(qbase + (m * 16 + (lane & 15)) * 64 + ks * 32 + (lane >> 4) * 8);
  }
  f32x4 accO[2][4] = {};
  float mrun[2][4], lrun[2][4];
#pragma unroll
  for (int m = 0; m < 2; ++m)
#pragma unroll
    for (int j = 0; j < 4; ++j) { mrun[m][j] = -__builtin_inff(); lrun[m][j] = 0.f; }
  const unsigned short* kb0 = kb + ((size_t)b * KVH_ + g * 2) * S_ * HD_;
  const unsigned short* vb0 = vb + ((size_t)b * KVH_ + g * 2) * S_ * HD_;
  const int str = tid >> 3, stc = (tid & 7) * 8;
  const int mr = tid >> 4, mc = (tid & 15) * 4;
  for (int kt = 0; kt < S_; kt += 64) {
    __syncthreads();
#pragma unroll
    for (int t = 0; t < 2; ++t) {
      gload_lds16(kb0 + ((size_t)t * S_ + kt + str) * HD_ + stc, (void*)(Ks + t * 4096 + tid * 8));
      gload_lds16(vb0 + ((size_t)t * HD_ + str) * S_ + kt + stc, (void*)(Vs + t * 4096 + tid * 8));
    }
    gload_lds16(mask + (size_t)mr * S_ + kt + mc, (void*)(Ms + tid * 4));
    __syncthreads();
    f32x4 sa[2][4] = {};
#pragma unroll
    for (int ks = 0; ks < 2; ++ks) {
      const int fc = ks * 32 + (lane >> 4) * 8;
      short8 bk[4];
#pragma unroll
      for (int n = 0; n < 4; ++n)
        bk[n] = *(const short8*)&Ks[kvl * 4096 + (n * 16 + (lane & 15)) * 64 + fc];
#pragma unroll
      for (int m = 0; m < 2; ++m)
#pragma unroll
        for (int n = 0; n < 4; ++n)
          sa[m][n] = __builtin_amdgcn_mfma_f32_16x16x32_bf16(aq[m][ks], bk[n], sa[m][n], 0, 0, 0);
    }
    // online softmax (rows live on 16-lane groups; butterfly over lane&15)
#pragma unroll
    for (int m = 0; m < 2; ++m)
#pragma unroll
      for (int j = 0; j < 4; ++j) {
        const int row = m * 16 + (lane >> 4) * 4 + j;
        float tmax = -__builtin_inff();
#pragma unroll
        for (int n = 0; n < 4; ++n) {
          float v = sa[m][n][j] * 0.125f + Ms[row * 64 + n * 16 + (lane & 15)];
          sa[m][n][j] = v;
          tmax = fmaxf(tmax, v);
        }
        tmax = fmaxf(tmax, __shfl_xor(tmax, 1));
        tmax = fmaxf(tmax, __shfl_xor(tmax, 2));
        tmax = fmaxf(tmax, __shfl_xor(tmax, 4));
        tmax = fmaxf(tmax, __shfl_xor(tmax, 8));
        const float mnew = fmaxf(mrun[m][j], tmax);
        const float es = __expf(mrun[m][j] - mnew);
        mrun[m][j] = mnew;
        float rs = 0.f;
#pragma unroll
        for (int n = 0; n < 4; ++n) {
          const float pv = __expf(sa[m][n][j] - mnew);
          sa[m][n][j] = pv;
          rs += pv;
        }
        rs += __shfl_xor(rs, 1);
        rs += __shfl_xor(rs, 2);
        rs += __shfl_xor(rs, 4);
        rs += __shfl_xor(rs, 8);
        lrun[m][j] = lrun[m][j] * es + rs;
#pragma unroll
        for (int n = 0; n < 4; ++n) {
          accO[m][n][j] *= es;
          Ps[w * 2048 + row * 64 + n * 16 + (lane & 15)] = f2bf(sa[m][n][j]);
        }
      }
    // PV: P (32 x 64) @ V^T-tile (Vs is [d][s_local])
#pragma unroll
    for (int ks = 0; ks < 2; ++ks) {
      const int fc = ks * 32 + (lane >> 4) * 8;
      short8 ap[2], bv[4];
#pragma unroll
      for (int m = 0; m < 2; ++m)
        ap[m] = *(const short8*)&Ps[w * 2048 + (m * 16 + (lane & 15)) * 64 + fc];
#pragma unroll
      for (int n = 0; n < 4; ++n)
        bv[n] = *(const short8*)&Vs[kvl * 4096 + (n * 16 + (lane & 15)) * 64 + fc];
#pragma unroll
      for (int m = 0; m < 2; ++m)
#pragma unroll
        for (int n = 0; n < 4; ++n)
          accO[m][n] = __builtin_amdgcn_mfma_f32_16x16x32_bf16(ap[m], bv[n], accO[m][n], 0, 0, 0);
    }
  }
#pragma unroll
  for (int m = 0; m < 2; ++m)
#pragma unroll
    for (int n = 0; n < 4; ++n)
#pragma unroll
      for (int j = 0; j < 4; ++j) {
        const int row = m * 16 + (lane >> 4) * 4 + j;
        const int t = b * S_ + qt * 32 + row;
        const int col = hq * 64 + n * 16 + (lane & 15);
        attnb[(size_t)t * (H_ * HD_) + col] = f2bf(accO[m][n][j] / lrun[m][j]);
      }
}

extern "C" void kernel_launch(void* const* d_in, const int* in_sizes, int n_in,
                              void* d_out, int out_size, void* d_ws, size_t ws_size,
                              hipStream_t stream) {
  (void)in_sizes; (void)n_in; (void)out_size; (void)ws_size;
  const float* x = (const float*)d_in[0];
  const float* fmask = (const float*)d_in[1];
  const float* tmask = (const float*)d_in[2];
  const float* wq = (const float*)d_in[3];
  const float* wk = (const float*)d_in[4];
  const float* wv = (const float*)d_in[5];
  const float* wo = (const float*)d_in[6];

  unsigned short* ws = (unsigned short*)d_ws;
  unsigned short* xb = ws;                                   // 4096x1024
  unsigned short* wqkvb = xb + (size_t)4096 * 1024;          // 1536x1024
  unsigned short* wob = wqkvb + (size_t)1536 * 1024;         // 1024x1024
  unsigned short* qbuf = wob + (size_t)1024 * 1024;          // [b][h][s][d]
  unsigned short* kbuf = qbuf + (size_t)4096 * 1024;         // [b][kvh][s][d]
  unsigned short* vbuf = kbuf + (size_t)1024 * 1024;         // [b][kvh][d][s]
  unsigned short* attnb = vbuf + (size_t)1024 * 1024;        // 4096x1024

  cast_kernel<<<4096, 256, 0, stream>>>(x, xb, 1048576);
  cast_kernel<<<1024, 256, 0, stream>>>(wq, wqkvb, 262144);
  cast_kernel<<<256, 256, 0, stream>>>(wk, wqkvb + (size_t)1024 * 1024, 65536);
  cast_kernel<<<256, 256, 0, stream>>>(wv, wqkvb + (size_t)1280 * 1024, 65536);
  cast_kernel<<<1024, 256, 0, stream>>>(wo, wob, 262144);

  gemm_bt<1><<<32 * 12, 256, 0, stream>>>(xb, wqkvb, nullptr, qbuf, kbuf, vbuf,
                                          4096, 1536, 1024, 12);
  attn_kernel<<<256, 512, 0, stream>>>(qbuf, kbuf, vbuf, fmask, tmask, attnb);
  gemm_bt<0><<<32 * 8, 256, 0, stream>>>(attnb, wob, (float*)d_out,
                                         nullptr, nullptr, nullptr, 4096, 1024, 1024, 8);
}

// Round 3
// 155.835 us; speedup vs baseline: 1.4758x; 1.4758x over previous
//
#include <hip/hip_runtime.h>
#include <hip/hip_bf16.h>

#define B_ 2
#define S_ 2048
#define D_ 1024
#define H_ 16
#define KVH_ 4
#define HD_ 64

typedef __attribute__((ext_vector_type(4))) float f32x4;
typedef __attribute__((ext_vector_type(16))) float f32x16;
typedef __attribute__((ext_vector_type(8))) short short8;

#define DEV static __device__ __forceinline__

DEV unsigned short f2bf(float f) {
  union { float f; unsigned int u; } v; v.f = f;
  unsigned int r = v.u + 0x7FFFu + ((v.u >> 16) & 1u);
  return (unsigned short)(r >> 16);
}

DEV void gload_lds16(const void* g, void* l) {
  __builtin_amdgcn_global_load_lds(
      (const __attribute__((address_space(1))) unsigned int*)g,
      (__attribute__((address_space(3))) unsigned int*)l, 16, 0, 0);
}

__global__ __launch_bounds__(256) void cast_kernel(const float* __restrict__ src,
                                                   unsigned short* __restrict__ dst, int n4) {
  int i = blockIdx.x * 256 + threadIdx.x;
  if (i >= n4) return;
  float4 v = ((const float4*)src)[i];
  ushort4 o;
  o.x = f2bf(v.x); o.y = f2bf(v.y); o.z = f2bf(v.z); o.w = f2bf(v.w);
  ((ushort4*)dst)[i] = o;
}

// C = A (M x K, bf16 row-major) @ Bw^T (Bw is N x K bf16 row-major)
// MODE 0: plain fp32 C. MODE 1: qkv scatter (bf16): cols 0-1023 -> q[b][h][s][d],
// 1024-1279 -> k[b][kvh][s][d], 1280-1535 -> v[b][kvh][d][s] (transposed).
template <int MODE>
__global__ __launch_bounds__(256) void gemm_bt(
    const unsigned short* __restrict__ A, const unsigned short* __restrict__ Bw,
    float* __restrict__ C, unsigned short* __restrict__ qb,
    unsigned short* __restrict__ kb, unsigned short* __restrict__ vb,
    int M, int N, int K, int ntn) {
  __shared__ __align__(16) unsigned short As[128 * 64];
  __shared__ __align__(16) unsigned short Bs[128 * 64];
  const int tid = threadIdx.x;
  const int lane = tid & 63, wid = tid >> 6;
  const int wr = wid >> 1, wc = wid & 1;
  const int tm = blockIdx.x / ntn, tn = blockIdx.x % ntn;
  const int row0 = tm * 128, col0 = tn * 128;
  f32x4 acc[4][4] = {};
  const int sr = tid >> 3, sc = (tid & 7) * 8;
  for (int kt = 0; kt < K; kt += 64) {
    __syncthreads();
#pragma unroll
    for (int i = 0; i < 4; ++i) {
      gload_lds16(A + (size_t)(row0 + i * 32 + sr) * K + kt + sc,
                  (void*)(As + i * 2048 + tid * 8));
      gload_lds16(Bw + (size_t)(col0 + i * 32 + sr) * K + kt + sc,
                  (void*)(Bs + i * 2048 + tid * 8));
    }
    __syncthreads();
#pragma unroll
    for (int ks = 0; ks < 64; ks += 32) {
      const int fc = ks + (lane >> 4) * 8;
      short8 af[4], bf[4];
#pragma unroll
      for (int m = 0; m < 4; ++m)
        af[m] = *(const short8*)&As[(wr * 64 + m * 16 + (lane & 15)) * 64 + fc];
#pragma unroll
      for (int n = 0; n < 4; ++n)
        bf[n] = *(const short8*)&Bs[(wc * 64 + n * 16 + (lane & 15)) * 64 + fc];
#pragma unroll
      for (int m = 0; m < 4; ++m)
#pragma unroll
        for (int n = 0; n < 4; ++n)
          acc[m][n] = __builtin_amdgcn_mfma_f32_16x16x32_bf16(af[m], bf[n], acc[m][n], 0, 0, 0);
    }
  }
#pragma unroll
  for (int m = 0; m < 4; ++m)
#pragma unroll
    for (int n = 0; n < 4; ++n)
#pragma unroll
      for (int j = 0; j < 4; ++j) {
        const int grow = row0 + wr * 64 + m * 16 + (lane >> 4) * 4 + j;
        const int gcol = col0 + wc * 64 + n * 16 + (lane & 15);
        const float v = acc[m][n][j];
        if (MODE == 0) {
          C[(size_t)grow * N + gcol] = v;
        } else {
          const int b = grow >> 11, s = grow & 2047;
          const unsigned short hv = f2bf(v);
          if (gcol < 1024) {
            const int hh = gcol >> 6, d = gcol & 63;
            qb[(((size_t)b * H_ + hh) * S_ + s) * HD_ + d] = hv;
          } else if (gcol < 1280) {
            const int kk = (gcol - 1024) >> 6, d = gcol & 63;
            kb[(((size_t)b * KVH_ + kk) * S_ + s) * HD_ + d] = hv;
          } else {
            const int kk = (gcol - 1280) >> 6, d = gcol & 63;
            vb[(((size_t)b * KVH_ + kk) * HD_ + d) * S_ + s] = hv;
          }
        }
      }
}

// Swapped-QK^T flash attention, 32x32x16 MFMA.
// Block = (b, g, hh, qt): 4 waves = 4 heads (one kv-head), 32 q-rows, kv loop of 64.
// Lane owns q = lane&31 (both halves); softmax lane-local; P->A-frag via pack+shfl(^32).
// K/V/mask LDS tiles XOR-swizzled (16B blk ^ row) with pre-swizzled gload_lds sources.
__global__ __launch_bounds__(256) void attn_kernel(
    const unsigned short* __restrict__ qb, const unsigned short* __restrict__ kb,
    const unsigned short* __restrict__ vb, const float* __restrict__ fmask,
    const float* __restrict__ tmask, unsigned short* __restrict__ attnb) {
  __shared__ __align__(16) unsigned short Ks[2][64 * 64];   // [kv][d]
  __shared__ __align__(16) unsigned short Vs[2][64 * 64];   // [d][kv]
  __shared__ __align__(16) float Ms[2][32 * 64];            // [q][kv]
  const int tid = threadIdx.x;
  const int lane = tid & 63, w = tid >> 6;
  const int l31 = lane & 31, hi = lane >> 5;

  // XCD-chunked swizzle: consecutive swz ids (hh pairs / qt neighbors) share an XCD.
  const int swz = (blockIdx.x % 8) * 64 + blockIdx.x / 8;
  const int hh = swz & 1, qt = (swz >> 1) & 63, g = (swz >> 7) & 1, b = swz >> 8;
  const int h = g * 8 + hh * 4 + w;
  const int kvh = g * 2 + hh;

  const unsigned short* kbase = kb + ((size_t)b * KVH_ + kvh) * S_ * HD_;
  const unsigned short* vbase = vb + ((size_t)b * KVH_ + kvh) * S_ * HD_;  // [d][s]
  const float* mbase = (g ? tmask : fmask) + (size_t)b * S_ * S_;

  // Q fragments (B-operand): col=q=lane&31, k = ks*16 + hi*8 + e
  short8 bq[4];
  {
    const unsigned short* qrow =
        qb + (((size_t)b * H_ + h) * S_ + qt * 32 + l31) * HD_;
#pragma unroll
    for (int ks = 0; ks < 4; ++ks)
      bq[ks] = *(const short8*)(qrow + ks * 16 + hi * 8);
  }

  f32x16 accO[2] = {};
  float mrow = -1e30f, lrow = 0.f;

  const int krow = tid >> 3, kblk = tid & 7;      // K/V stage coords (rows 0..31, +32)
  const int mrow_s = tid >> 4, mblk = tid & 15;   // mask stage coords (rows 0..15, +16)

  // 6 x 16B loads per thread per tile: K rows 0-31 & 32-63, V d-rows 0-31 & 32-63,
  // mask q-rows 0-15 & 16-31. Swizzles stay consistent: (r+32)&7==r&7, (r+16)&15==r&15.
#define STAGE(KT, BUF)                                                                   \
  do {                                                                                   \
    gload_lds16(kbase + (size_t)((KT) + krow) * 64 + ((kblk ^ (krow & 7)) << 3),         \
                (void*)&Ks[BUF][tid * 8]);                                               \
    gload_lds16(kbase + (size_t)((KT) + 32 + krow) * 64 + ((kblk ^ (krow & 7)) << 3),    \
                (void*)&Ks[BUF][2048 + tid * 8]);                                        \
    gload_lds16(vbase + (size_t)krow * 2048 + (KT) + ((kblk ^ (krow & 7)) << 3),         \
                (void*)&Vs[BUF][tid * 8]);                                               \
    gload_lds16(vbase + (size_t)(32 + krow) * 2048 + (KT) + ((kblk ^ (krow & 7)) << 3),  \
                (void*)&Vs[BUF][2048 + tid * 8]);                                        \
    gload_lds16(mbase + (size_t)(qt * 32 + mrow_s) * 2048 + (KT) +                       \
                    ((mblk ^ (mrow_s & 15)) << 2),                                       \
                (void*)&Ms[BUF][tid * 4]);                                               \
    gload_lds16(mbase + (size_t)(qt * 32 + 16 + mrow_s) * 2048 + (KT) +                  \
                    ((mblk ^ (mrow_s & 15)) << 2),                                       \
                (void*)&Ms[BUF][1024 + tid * 4]);                                        \
  } while (0)

  STAGE(0, 0);
  for (int t = 0; t < 32; ++t) {
    const int cur = t & 1;
    if (t + 1 < 32) {
      STAGE((t + 1) * 64, cur ^ 1);
      asm volatile("s_waitcnt vmcnt(6)" ::: "memory");
    } else {
      asm volatile("s_waitcnt vmcnt(0)" ::: "memory");
    }
    __builtin_amdgcn_s_barrier();
    __builtin_amdgcn_sched_barrier(0);

    const unsigned short* ksb = Ks[cur];
    const unsigned short* vsb = Vs[cur];
    const float* msb = Ms[cur];

    // QK^T swapped: A=K (row=kv=lane&31), B=Q (col=q=lane&31).
    // s[u] reg r holds logit[q = l31][kv = u*32 + (r&3)+8*(r>>2)+4*hi]
    f32x16 s[2] = {};
#pragma unroll
    for (int u = 0; u < 2; ++u)
#pragma unroll
      for (int ks = 0; ks < 4; ++ks) {
        short8 ak = *(const short8*)&ksb[(u * 32 + l31) * 64 +
                                         (((ks * 2 + hi) ^ (lane & 7)) << 3)];
        s[u] = __builtin_amdgcn_mfma_f32_32x32x16_bf16(ak, bq[ks], s[u], 0, 0, 0);
      }

    // scale + mask + tile max (lane-local row)
    float tmax = -1e30f;
#pragma unroll
    for (int u = 0; u < 2; ++u)
#pragma unroll
      for (int rg = 0; rg < 4; ++rg) {
        f32x4 mk = *(const f32x4*)&msb[l31 * 64 +
                                       (((u * 8 + rg * 2 + hi) ^ (lane & 15)) << 2)];
#pragma unroll
        for (int e = 0; e < 4; ++e) {
          float v = s[u][rg * 4 + e] * 0.125f + mk[e];
          s[u][rg * 4 + e] = v;
          tmax = fmaxf(tmax, v);
        }
      }
    tmax = fmaxf(tmax, __shfl_xor(tmax, 32));

    // defer-max: rescale only when max grows past threshold
    if (__any(tmax > mrow + 8.f)) {
      const float mnew = fmaxf(mrow, tmax);
      const float es = __expf(mrow - mnew);
      mrow = mnew;
      lrow *= es;
#pragma unroll
      for (int r = 0; r < 16; ++r) {
        const float esb = __shfl(es, (r & 3) + 8 * (r >> 2) + 4 * hi);
        accO[0][r] *= esb;
        accO[1][r] *= esb;
      }
    }

    float rs = 0.f;
#pragma unroll
    for (int u = 0; u < 2; ++u)
#pragma unroll
      for (int r = 0; r < 16; ++r) {
        const float p = __expf(s[u][r] - mrow);
        s[u][r] = p;
        rs += p;
      }
    rs += __shfl_xor(rs, 32);
    lrow += rs;

    // P -> bf16 A-fragments (in-register, shfl(^32) redistribution) + PV
#pragma unroll
    for (int u = 0; u < 2; ++u) {
      unsigned int Dw[8], Sw[8];
#pragma unroll
      for (int i = 0; i < 8; ++i)
        Dw[i] = (unsigned int)f2bf(s[u][2 * i]) |
                ((unsigned int)f2bf(s[u][2 * i + 1]) << 16);
#pragma unroll
      for (int i = 0; i < 8; ++i)
        Sw[i] = (unsigned int)__shfl_xor((int)Dw[i], 32);
      short8 ap[2];
#pragma unroll
      for (int k2 = 0; k2 < 2; ++k2) {
        union { unsigned int wd[4]; short8 v; } cv;
        const int b0 = k2 * 4;
        cv.wd[0] = hi ? Sw[b0 + 2] : Dw[b0 + 0];
        cv.wd[1] = hi ? Sw[b0 + 3] : Dw[b0 + 1];
        cv.wd[2] = hi ? Dw[b0 + 2] : Sw[b0 + 0];
        cv.wd[3] = hi ? Dw[b0 + 3] : Sw[b0 + 1];
        ap[k2] = cv.v;
      }
#pragma unroll
      for (int dt = 0; dt < 2; ++dt)
#pragma unroll
        for (int k2 = 0; k2 < 2; ++k2) {
          short8 bv = *(const short8*)&vsb[(dt * 32 + l31) * 64 +
                                           (((u * 4 + k2 * 2 + hi) ^ (lane & 7)) << 3)];
          accO[dt] = __builtin_amdgcn_mfma_f32_32x32x16_bf16(ap[k2], bv, accO[dt], 0, 0, 0);
        }
    }
    __builtin_amdgcn_s_barrier();
    __builtin_amdgcn_sched_barrier(0);
  }
#undef STAGE

  // epilogue: O[q = crow][d = dt*32 + l31] / l[q]
#pragma unroll
  for (int r = 0; r < 16; ++r) {
    const int crow = (r & 3) + 8 * (r >> 2) + 4 * hi;
    const float linv = 1.0f / __shfl(lrow, crow);
    const size_t o = (size_t)(b * S_ + qt * 32 + crow) * (H_ * HD_) + h * 64 + l31;
    attnb[o] = f2bf(accO[0][r] * linv);
    attnb[o + 32] = f2bf(accO[1][r] * linv);
  }
}

extern "C" void kernel_launch(void* const* d_in, const int* in_sizes, int n_in,
                              void* d_out, int out_size, void* d_ws, size_t ws_size,
                              hipStream_t stream) {
  (void)in_sizes; (void)n_in; (void)out_size; (void)ws_size;
  const float* x = (const float*)d_in[0];
  const float* fmask = (const float*)d_in[1];
  const float* tmask = (const float*)d_in[2];
  const float* wq = (const float*)d_in[3];
  const float* wk = (const float*)d_in[4];
  const float* wv = (const float*)d_in[5];
  const float* wo = (const float*)d_in[6];

  unsigned short* ws = (unsigned short*)d_ws;
  unsigned short* xb = ws;                                   // 4096x1024
  unsigned short* wqkvb = xb + (size_t)4096 * 1024;          // 1536x1024
  unsigned short* wob = wqkvb + (size_t)1536 * 1024;         // 1024x1024
  unsigned short* qbuf = wob + (size_t)1024 * 1024;          // [b][h][s][d]
  unsigned short* kbuf = qbuf + (size_t)4096 * 1024;         // [b][kvh][s][d]
  unsigned short* vbuf = kbuf + (size_t)1024 * 1024;         // [b][kvh][d][s]
  unsigned short* attnb = vbuf + (size_t)1024 * 1024;        // 4096x1024

  cast_kernel<<<4096, 256, 0, stream>>>(x, xb, 1048576);
  cast_kernel<<<1024, 256, 0, stream>>>(wq, wqkvb, 262144);
  cast_kernel<<<256, 256, 0, stream>>>(wk, wqkvb + (size_t)1024 * 1024, 65536);
  cast_kernel<<<256, 256, 0, stream>>>(wv, wqkvb + (size_t)1280 * 1024, 65536);
  cast_kernel<<<1024, 256, 0, stream>>>(wo, wob, 262144);

  gemm_bt<1><<<32 * 12, 256, 0, stream>>>(xb, wqkvb, nullptr, qbuf, kbuf, vbuf,
                                          4096, 1536, 1024, 12);
  attn_kernel<<<512, 256, 0, stream>>>(qbuf, kbuf, vbuf, fmask, tmask, attnb);
  gemm_bt<0><<<32 * 8, 256, 0, stream>>>(attnb, wob, (float*)d_out,
                                         nullptr, nullptr, nullptr, 4096, 1024, 1024, 8);
}

// Round 4
// 151.524 us; speedup vs baseline: 1.5178x; 1.0285x over previous
//
#include <hip/hip_runtime.h>
#include <hip/hip_bf16.h>

#define B_ 2
#define S_ 2048
#define D_ 1024
#define H_ 16
#define KVH_ 4
#define HD_ 64

#define LOG2E 1.44269504089f
#define QSCALE 0.18033688011f  // 0.125 * log2(e)

typedef __attribute__((ext_vector_type(4))) float f32x4;
typedef __attribute__((ext_vector_type(16))) float f32x16;
typedef __attribute__((ext_vector_type(8))) short short8;

#define DEV static __device__ __forceinline__

DEV unsigned short f2bf(float f) {
  union { float f; unsigned int u; } v; v.f = f;
  unsigned int r = v.u + 0x7FFFu + ((v.u >> 16) & 1u);
  return (unsigned short)(r >> 16);
}

DEV float fexp2(float x) {
#if __has_builtin(__builtin_amdgcn_exp2f)
  return __builtin_amdgcn_exp2f(x);
#else
  float r;
  asm("v_exp_f32 %0, %1" : "=v"(r) : "v"(x));
  return r;
#endif
}

DEV unsigned int pack_bf16(float lo, float hi) {
  float2 f2; f2.x = lo; f2.y = hi;
  __hip_bfloat162 h2 = __float22bfloat162_rn(f2);
  union { __hip_bfloat162 h; unsigned int u; } cv;
  cv.h = h2;
  return cv.u;
}

DEV void gload_lds16(const void* g, void* l) {
  __builtin_amdgcn_global_load_lds(
      (const __attribute__((address_space(1))) unsigned int*)g,
      (__attribute__((address_space(3))) unsigned int*)l, 16, 0, 0);
}

__global__ __launch_bounds__(256) void cast_kernel(const float* __restrict__ src,
                                                   unsigned short* __restrict__ dst, int n4) {
  int i = blockIdx.x * 256 + threadIdx.x;
  if (i >= n4) return;
  float4 v = ((const float4*)src)[i];
  ushort4 o;
  o.x = f2bf(v.x); o.y = f2bf(v.y); o.z = f2bf(v.z); o.w = f2bf(v.w);
  ((ushort4*)dst)[i] = o;
}

// C = A (M x K, bf16 row-major) @ Bw^T (Bw is N x K bf16 row-major)
// MODE 0: plain fp32 C. MODE 1: qkv scatter (bf16): cols 0-1023 -> q[b][h][s][d]
// (pre-scaled by 0.125*log2e for exp2-domain softmax), 1024-1279 -> k[b][kvh][s][d],
// 1280-1535 -> v[b][kvh][d][s] (transposed).
template <int MODE>
__global__ __launch_bounds__(256) void gemm_bt(
    const unsigned short* __restrict__ A, const unsigned short* __restrict__ Bw,
    float* __restrict__ C, unsigned short* __restrict__ qb,
    unsigned short* __restrict__ kb, unsigned short* __restrict__ vb,
    int M, int N, int K, int ntn) {
  __shared__ __align__(16) unsigned short As[128 * 64];
  __shared__ __align__(16) unsigned short Bs[128 * 64];
  const int tid = threadIdx.x;
  const int lane = tid & 63, wid = tid >> 6;
  const int wr = wid >> 1, wc = wid & 1;
  const int tm = blockIdx.x / ntn, tn = blockIdx.x % ntn;
  const int row0 = tm * 128, col0 = tn * 128;
  f32x4 acc[4][4] = {};
  const int sr = tid >> 3, sc = (tid & 7) * 8;
  for (int kt = 0; kt < K; kt += 64) {
    __syncthreads();
#pragma unroll
    for (int i = 0; i < 4; ++i) {
      gload_lds16(A + (size_t)(row0 + i * 32 + sr) * K + kt + sc,
                  (void*)(As + i * 2048 + tid * 8));
      gload_lds16(Bw + (size_t)(col0 + i * 32 + sr) * K + kt + sc,
                  (void*)(Bs + i * 2048 + tid * 8));
    }
    __syncthreads();
#pragma unroll
    for (int ks = 0; ks < 64; ks += 32) {
      const int fc = ks + (lane >> 4) * 8;
      short8 af[4], bf[4];
#pragma unroll
      for (int m = 0; m < 4; ++m)
        af[m] = *(const short8*)&As[(wr * 64 + m * 16 + (lane & 15)) * 64 + fc];
#pragma unroll
      for (int n = 0; n < 4; ++n)
        bf[n] = *(const short8*)&Bs[(wc * 64 + n * 16 + (lane & 15)) * 64 + fc];
#pragma unroll
      for (int m = 0; m < 4; ++m)
#pragma unroll
        for (int n = 0; n < 4; ++n)
          acc[m][n] = __builtin_amdgcn_mfma_f32_16x16x32_bf16(af[m], bf[n], acc[m][n], 0, 0, 0);
    }
  }
#pragma unroll
  for (int m = 0; m < 4; ++m)
#pragma unroll
    for (int n = 0; n < 4; ++n)
#pragma unroll
      for (int j = 0; j < 4; ++j) {
        const int grow = row0 + wr * 64 + m * 16 + (lane >> 4) * 4 + j;
        const int gcol = col0 + wc * 64 + n * 16 + (lane & 15);
        const float v = acc[m][n][j];
        if (MODE == 0) {
          C[(size_t)grow * N + gcol] = v;
        } else {
          const int b = grow >> 11, s = grow & 2047;
          if (gcol < 1024) {
            const int hh = gcol >> 6, d = gcol & 63;
            qb[(((size_t)b * H_ + hh) * S_ + s) * HD_ + d] = f2bf(v * QSCALE);
          } else if (gcol < 1280) {
            const int kk = (gcol - 1024) >> 6, d = gcol & 63;
            kb[(((size_t)b * KVH_ + kk) * S_ + s) * HD_ + d] = f2bf(v);
          } else {
            const int kk = (gcol - 1280) >> 6, d = gcol & 63;
            vb[(((size_t)b * KVH_ + kk) * HD_ + d) * S_ + s] = f2bf(v);
          }
        }
      }
}

// Swapped-QK^T flash attention, 32x32x16 MFMA, exp2-domain online softmax.
// Block = (b, g, hh, qt): 4 waves = 4 heads (one kv-head), 32 q-rows, kv loop of 64.
// Lane owns q = lane&31; softmax lane-local; P->A-frag via cvt_pk + shfl(^32).
__global__ __launch_bounds__(256) void attn_kernel(
    const unsigned short* __restrict__ qb, const unsigned short* __restrict__ kb,
    const unsigned short* __restrict__ vb, const float* __restrict__ fmask,
    const float* __restrict__ tmask, unsigned short* __restrict__ attnb) {
  __shared__ __align__(16) unsigned short Ks[2][64 * 64];   // [kv][d]
  __shared__ __align__(16) unsigned short Vs[2][64 * 64];   // [d][kv]
  __shared__ __align__(16) float Ms[2][32 * 64];            // [q][kv]
  const int tid = threadIdx.x;
  const int lane = tid & 63, w = tid >> 6;
  const int l31 = lane & 31, hi = lane >> 5;

  // XCD-chunked swizzle: consecutive swz ids (hh pairs / qt neighbors) share an XCD.
  const int swz = (blockIdx.x % 8) * 64 + blockIdx.x / 8;
  const int hh = swz & 1, qt = (swz >> 1) & 63, g = (swz >> 7) & 1, b = swz >> 8;
  const int h = g * 8 + hh * 4 + w;
  const int kvh = g * 2 + hh;

  const unsigned short* kbase = kb + ((size_t)b * KVH_ + kvh) * S_ * HD_;
  const unsigned short* vbase = vb + ((size_t)b * KVH_ + kvh) * S_ * HD_;  // [d][s]
  const float* mbase = (g ? tmask : fmask) + (size_t)b * S_ * S_;

  // Q fragments (B-operand): col=q=lane&31, k = ks*16 + hi*8 + e
  short8 bq[4];
  {
    const unsigned short* qrow =
        qb + (((size_t)b * H_ + h) * S_ + qt * 32 + l31) * HD_;
#pragma unroll
    for (int ks = 0; ks < 4; ++ks)
      bq[ks] = *(const short8*)(qrow + ks * 16 + hi * 8);
  }

  f32x16 accO[2] = {};
  float mrow = -1e30f, lrow = 0.f;  // mrow in log2 domain

  const int krow = tid >> 3, kblk = tid & 7;      // K/V stage coords (rows 0..31, +32)
  const int mrow_s = tid >> 4, mblk = tid & 15;   // mask stage coords (rows 0..15, +16)

  // 6 x 16B loads per thread per tile. Swizzles: (r+32)&7==r&7, (r+16)&15==r&15.
#define STAGE(KT, BUF)                                                                   \
  do {                                                                                   \
    gload_lds16(kbase + (size_t)((KT) + krow) * 64 + ((kblk ^ (krow & 7)) << 3),         \
                (void*)&Ks[BUF][tid * 8]);                                               \
    gload_lds16(kbase + (size_t)((KT) + 32 + krow) * 64 + ((kblk ^ (krow & 7)) << 3),    \
                (void*)&Ks[BUF][2048 + tid * 8]);                                        \
    gload_lds16(vbase + (size_t)krow * 2048 + (KT) + ((kblk ^ (krow & 7)) << 3),         \
                (void*)&Vs[BUF][tid * 8]);                                               \
    gload_lds16(vbase + (size_t)(32 + krow) * 2048 + (KT) + ((kblk ^ (krow & 7)) << 3),  \
                (void*)&Vs[BUF][2048 + tid * 8]);                                        \
    gload_lds16(mbase + (size_t)(qt * 32 + mrow_s) * 2048 + (KT) +                       \
                    ((mblk ^ (mrow_s & 15)) << 2),                                       \
                (void*)&Ms[BUF][tid * 4]);                                               \
    gload_lds16(mbase + (size_t)(qt * 32 + 16 + mrow_s) * 2048 + (KT) +                  \
                    ((mblk ^ (mrow_s & 15)) << 2),                                       \
                (void*)&Ms[BUF][1024 + tid * 4]);                                        \
  } while (0)

  STAGE(0, 0);
#pragma unroll 2
  for (int t = 0; t < 32; ++t) {
    const int cur = t & 1;
    if (t + 1 < 32) {
      STAGE((t + 1) * 64, cur ^ 1);
      asm volatile("s_waitcnt vmcnt(6)" ::: "memory");
    } else {
      asm volatile("s_waitcnt vmcnt(0)" ::: "memory");
    }
    __builtin_amdgcn_s_barrier();
    __builtin_amdgcn_sched_barrier(0);

    const unsigned short* ksb = Ks[cur];
    const unsigned short* vsb = Vs[cur];
    const float* msb = Ms[cur];

    // QK^T swapped: A=K (row=kv=lane&31), B=Q (col=q=lane&31).
    // s[u] reg r holds logit2[q = l31][kv = u*32 + (r&3)+8*(r>>2)+4*hi] (log2 domain)
    f32x16 s[2] = {};
    __builtin_amdgcn_s_setprio(1);
#pragma unroll
    for (int u = 0; u < 2; ++u)
#pragma unroll
      for (int ks = 0; ks < 4; ++ks) {
        short8 ak = *(const short8*)&ksb[(u * 32 + l31) * 64 +
                                         (((ks * 2 + hi) ^ (lane & 7)) << 3)];
        s[u] = __builtin_amdgcn_mfma_f32_32x32x16_bf16(ak, bq[ks], s[u], 0, 0, 0);
      }
    __builtin_amdgcn_s_setprio(0);

    // mask add (log2 domain) + tile max (pairwise for v_max3 fusion)
    float tmax0 = -1e30f, tmax1 = -1e30f;
#pragma unroll
    for (int u = 0; u < 2; ++u)
#pragma unroll
      for (int rg = 0; rg < 4; ++rg) {
        f32x4 mk = *(const f32x4*)&msb[l31 * 64 +
                                       (((u * 8 + rg * 2 + hi) ^ (lane & 15)) << 2)];
        float v0 = fmaf(mk[0], LOG2E, s[u][rg * 4 + 0]);
        float v1 = fmaf(mk[1], LOG2E, s[u][rg * 4 + 1]);
        float v2 = fmaf(mk[2], LOG2E, s[u][rg * 4 + 2]);
        float v3 = fmaf(mk[3], LOG2E, s[u][rg * 4 + 3]);
        s[u][rg * 4 + 0] = v0;
        s[u][rg * 4 + 1] = v1;
        s[u][rg * 4 + 2] = v2;
        s[u][rg * 4 + 3] = v3;
        tmax0 = fmaxf(tmax0, fmaxf(v0, v1));
        tmax1 = fmaxf(tmax1, fmaxf(v2, v3));
      }
    float tmax = fmaxf(tmax0, tmax1);
    tmax = fmaxf(tmax, __shfl_xor(tmax, 32));

    // defer-max (threshold 8 nats = 11.5 in log2)
    if (__any(tmax > mrow + 11.5f)) {
      const float mnew = fmaxf(mrow, tmax);
      const float es = fexp2(mrow - mnew);
      mrow = mnew;
      lrow *= es;
#pragma unroll
      for (int r = 0; r < 16; ++r) {
        const float esb = __shfl(es, (r & 3) + 8 * (r >> 2) + 4 * hi);
        accO[0][r] *= esb;
        accO[1][r] *= esb;
      }
    }

    // p = exp2(s - mrow); 4-way sum tree
    float rs0 = 0.f, rs1 = 0.f, rs2 = 0.f, rs3 = 0.f;
#pragma unroll
    for (int u = 0; u < 2; ++u)
#pragma unroll
      for (int r = 0; r < 16; r += 4) {
        float p0 = fexp2(s[u][r + 0] - mrow);
        float p1 = fexp2(s[u][r + 1] - mrow);
        float p2 = fexp2(s[u][r + 2] - mrow);
        float p3 = fexp2(s[u][r + 3] - mrow);
        s[u][r + 0] = p0; s[u][r + 1] = p1; s[u][r + 2] = p2; s[u][r + 3] = p3;
        rs0 += p0; rs1 += p1; rs2 += p2; rs3 += p3;
      }
    float rs = (rs0 + rs1) + (rs2 + rs3);
    rs += __shfl_xor(rs, 32);
    lrow += rs;

    // P -> bf16 A-fragments (v_cvt_pk_bf16_f32 + shfl(^32) redistribution) + PV
#pragma unroll
    for (int u = 0; u < 2; ++u) {
      unsigned int Dw[8], Sw[8];
#pragma unroll
      for (int i = 0; i < 8; ++i)
        Dw[i] = pack_bf16(s[u][2 * i], s[u][2 * i + 1]);
#pragma unroll
      for (int i = 0; i < 8; ++i)
        Sw[i] = (unsigned int)__shfl_xor((int)Dw[i], 32);
      short8 ap[2];
#pragma unroll
      for (int k2 = 0; k2 < 2; ++k2) {
        union { unsigned int wd[4]; short8 v; } cv;
        const int b0 = k2 * 4;
        cv.wd[0] = hi ? Sw[b0 + 2] : Dw[b0 + 0];
        cv.wd[1] = hi ? Sw[b0 + 3] : Dw[b0 + 1];
        cv.wd[2] = hi ? Dw[b0 + 2] : Sw[b0 + 0];
        cv.wd[3] = hi ? Dw[b0 + 3] : Sw[b0 + 1];
        ap[k2] = cv.v;
      }
      __builtin_amdgcn_s_setprio(1);
#pragma unroll
      for (int dt = 0; dt < 2; ++dt)
#pragma unroll
        for (int k2 = 0; k2 < 2; ++k2) {
          short8 bv = *(const short8*)&vsb[(dt * 32 + l31) * 64 +
                                           (((u * 4 + k2 * 2 + hi) ^ (lane & 7)) << 3)];
          accO[dt] = __builtin_amdgcn_mfma_f32_32x32x16_bf16(ap[k2], bv, accO[dt], 0, 0, 0);
        }
      __builtin_amdgcn_s_setprio(0);
    }
    __builtin_amdgcn_s_barrier();
    __builtin_amdgcn_sched_barrier(0);
  }
#undef STAGE

  // epilogue: O[q = crow][d = dt*32 + l31] / l[q]
#pragma unroll
  for (int r = 0; r < 16; ++r) {
    const int crow = (r & 3) + 8 * (r >> 2) + 4 * hi;
    const float linv = 1.0f / __shfl(lrow, crow);
    const size_t o = (size_t)(b * S_ + qt * 32 + crow) * (H_ * HD_) + h * 64 + l31;
    attnb[o] = f2bf(accO[0][r] * linv);
    attnb[o + 32] = f2bf(accO[1][r] * linv);
  }
}

extern "C" void kernel_launch(void* const* d_in, const int* in_sizes, int n_in,
                              void* d_out, int out_size, void* d_ws, size_t ws_size,
                              hipStream_t stream) {
  (void)in_sizes; (void)n_in; (void)out_size; (void)ws_size;
  const float* x = (const float*)d_in[0];
  const float* fmask = (const float*)d_in[1];
  const float* tmask = (const float*)d_in[2];
  const float* wq = (const float*)d_in[3];
  const float* wk = (const float*)d_in[4];
  const float* wv = (const float*)d_in[5];
  const float* wo = (const float*)d_in[6];

  unsigned short* ws = (unsigned short*)d_ws;
  unsigned short* xb = ws;                                   // 4096x1024
  unsigned short* wqkvb = xb + (size_t)4096 * 1024;          // 1536x1024
  unsigned short* wob = wqkvb + (size_t)1536 * 1024;         // 1024x1024
  unsigned short* qbuf = wob + (size_t)1024 * 1024;          // [b][h][s][d]
  unsigned short* kbuf = qbuf + (size_t)4096 * 1024;         // [b][kvh][s][d]
  unsigned short* vbuf = kbuf + (size_t)1024 * 1024;         // [b][kvh][d][s]
  unsigned short* attnb = vbuf + (size_t)1024 * 1024;        // 4096x1024

  cast_kernel<<<4096, 256, 0, stream>>>(x, xb, 1048576);
  cast_kernel<<<1024, 256, 0, stream>>>(wq, wqkvb, 262144);
  cast_kernel<<<256, 256, 0, stream>>>(wk, wqkvb + (size_t)1024 * 1024, 65536);
  cast_kernel<<<256, 256, 0, stream>>>(wv, wqkvb + (size_t)1280 * 1024, 65536);
  cast_kernel<<<1024, 256, 0, stream>>>(wo, wob, 262144);

  gemm_bt<1><<<32 * 12, 256, 0, stream>>>(xb, wqkvb, nullptr, qbuf, kbuf, vbuf,
                                          4096, 1536, 1024, 12);
  attn_kernel<<<512, 256, 0, stream>>>(qbuf, kbuf, vbuf, fmask, tmask, attnb);
  gemm_bt<0><<<32 * 8, 256, 0, stream>>>(attnb, wob, (float*)d_out,
                                         nullptr, nullptr, nullptr, 4096, 1024, 1024, 8);
}